// Round 1
// 197.314 us; speedup vs baseline: 1.0532x; 1.0532x over previous
//
#include <hip/hip_runtime.h>
#include <hip/hip_bf16.h>
#include <math.h>

// ---- problem constants (structural, from the reference) ----
#define NB      2
#define QN      12240
#define HW_TOT  12240
#define DIMS    256
#define HEADS   8
#define CH      32
#define LEVELS  4
#define POINTS  4
#define M_TOT   (NB * QN)        // 24480

typedef unsigned short ushort_t;
typedef __attribute__((ext_vector_type(8))) short short8;
typedef __attribute__((ext_vector_type(4))) float floatx4;

__device__ __forceinline__ ushort_t f2bf(float f) {
    __hip_bfloat16 h = __float2bfloat16(f);
    return *reinterpret_cast<ushort_t*>(&h);
}

// =====================================================================
// Elementwise fp32 -> bf16 for v and q (one pass, 8 elems/thread).
// =====================================================================
__global__ __launch_bounds__(256) void convert_qv_kernel(
    const float* __restrict__ v, const float* __restrict__ q,
    ushort_t* __restrict__ vbf, ushort_t* __restrict__ qbf)
{
    const size_t i = ((size_t)blockIdx.x * 256 + threadIdx.x) * 8;
    const size_t half = (size_t)M_TOT * DIMS;
    const float* src; ushort_t* dst; size_t off;
    if (i < half) { src = v; dst = vbf; off = i; }
    else          { src = q; dst = qbf; off = i - half; }
    const float4 a = *(const float4*)&src[off];
    const float4 b = *(const float4*)&src[off + 4];
    ushort_t t[8] = {f2bf(a.x), f2bf(a.y), f2bf(a.z), f2bf(a.w),
                     f2bf(b.x), f2bf(b.y), f2bf(b.z), f2bf(b.w)};
    *(int4*)&dst[off] = *(int4*)t;
}

// =====================================================================
// Weights -> transposed bf16 (WT[n][k]); z=1 also builds the fused
// off+attn weight [384][256] and its combined bias.
// =====================================================================
__global__ __launch_bounds__(256) void prep_weights_kernel(
    const float* __restrict__ W_in, const float* __restrict__ W_off,
    const float* __restrict__ W_attn, const float* __restrict__ W_out,
    const float* __restrict__ b_off, const float* __restrict__ b_attn,
    ushort_t* __restrict__ Tin, ushort_t* __restrict__ Tcomb,
    ushort_t* __restrict__ Tout, float* __restrict__ bcomb)
{
    const int z  = blockIdx.z;
    const int gi = blockIdx.x * 256 + threadIdx.x;
    if (z == 1 && gi < 384)
        bcomb[gi] = (gi < 256) ? b_off[gi] : b_attn[gi - 256];
    const int Nw = (z == 1) ? 384 : 256;
    if (gi >= Nw * 256) return;
    const int k = gi & 255;       // coalesced write along k
    const int n = gi >> 8;
    float val; ushort_t* T;
    if (z == 0)      { val = W_in[k * 256 + n];  T = Tin;  }
    else if (z == 1) { val = (n < 256) ? W_off[k * 256 + n]
                                       : W_attn[k * 128 + (n - 256)]; T = Tcomb; }
    else             { val = W_out[k * 256 + n]; T = Tout; }
    T[n * 256 + k] = f2bf(val);
}

// =====================================================================
// m97-style bf16 MFMA GEMM core: C[M,Nc] = A[M,K] @ BT[Nc,K]^T + bias.
// (unchanged from previous round)
// =====================================================================
__device__ __forceinline__ void gemm_tile_core(
    const ushort_t* __restrict__ A, const ushort_t* __restrict__ BT,
    const float* __restrict__ bias, void* __restrict__ C, bool c_bf16,
    int M, int Nc, int bm0, int bn0, int K,
    ushort_t* As, ushort_t* Bs)
{
    const int tid  = threadIdx.x;
    const int wave = tid >> 6;
    const int lane = tid & 63;
    const int quad = lane >> 4;
    const int l16  = lane & 15;
    const int wm   = (wave >> 1) * 64;
    const int wn   = (wave & 1) * 64;

    const int off0 = tid * 16;
    const int row0 = off0 >> 6;
    const int kc0  = (off0 & 63) >> 1;

    int ar0 = bm0 + row0;      if (ar0 > M - 1) ar0 = M - 1;
    int ar1 = bm0 + row0 + 64; if (ar1 > M - 1) ar1 = M - 1;

    const ushort_t* ga0 = A  + (size_t)ar0 * K + kc0;
    const ushort_t* ga1 = A  + (size_t)ar1 * K + kc0;
    const ushort_t* gb0 = BT + (size_t)(bn0 + row0) * K + kc0;
    const ushort_t* gb1 = BT + (size_t)(bn0 + row0 + 64) * K + kc0;

    ushort_t* lA0 = As + wave * 512;
    ushort_t* lA1 = As + wave * 512 + 2048;
    ushort_t* lB0 = Bs + wave * 512;
    ushort_t* lB1 = Bs + wave * 512 + 2048;

    floatx4 acc[4][4];
    #pragma unroll
    for (int i = 0; i < 4; ++i)
        #pragma unroll
        for (int j = 0; j < 4; ++j)
            acc[i][j] = (floatx4){0.f, 0.f, 0.f, 0.f};

    for (int kk = 0; kk < K; kk += 32) {
        __builtin_amdgcn_global_load_lds(
            (const __attribute__((address_space(1))) void*)(ga0 + kk),
            (__attribute__((address_space(3))) void*)lA0, 16, 0, 0);
        __builtin_amdgcn_global_load_lds(
            (const __attribute__((address_space(1))) void*)(ga1 + kk),
            (__attribute__((address_space(3))) void*)lA1, 16, 0, 0);
        __builtin_amdgcn_global_load_lds(
            (const __attribute__((address_space(1))) void*)(gb0 + kk),
            (__attribute__((address_space(3))) void*)lB0, 16, 0, 0);
        __builtin_amdgcn_global_load_lds(
            (const __attribute__((address_space(1))) void*)(gb1 + kk),
            (__attribute__((address_space(3))) void*)lB1, 16, 0, 0);
        __syncthreads();

        short8 af[4], bfr[4];
        #pragma unroll
        for (int mt = 0; mt < 4; ++mt)
            af[mt] = *(const short8*)&As[(wm + mt * 16 + l16) * 32 + quad * 8];
        #pragma unroll
        for (int nt = 0; nt < 4; ++nt)
            bfr[nt] = *(const short8*)&Bs[(wn + nt * 16 + l16) * 32 + quad * 8];
        #pragma unroll
        for (int mt = 0; mt < 4; ++mt)
            #pragma unroll
            for (int nt = 0; nt < 4; ++nt)
                acc[mt][nt] = __builtin_amdgcn_mfma_f32_16x16x32_bf16(
                    af[mt], bfr[nt], acc[mt][nt], 0, 0, 0);
        __syncthreads();
    }

    #pragma unroll
    for (int mt = 0; mt < 4; ++mt) {
        #pragma unroll
        for (int j = 0; j < 4; ++j) {
            const int row = bm0 + wm + mt * 16 + quad * 4 + j;
            if (row >= M) continue;
            #pragma unroll
            for (int nt = 0; nt < 4; ++nt) {
                const int col = bn0 + wn + nt * 16 + l16;
                const float val = acc[mt][nt][j] + bias[col];
                if (c_bf16) ((ushort_t*)C)[(size_t)row * Nc + col] = f2bf(val);
                else        ((float*)C)[(size_t)row * Nc + col]    = val;
            }
        }
    }
}

__global__ __launch_bounds__(256) void gemm_proj_kernel(
    const ushort_t* __restrict__ vbf, const ushort_t* __restrict__ qbf,
    const ushort_t* __restrict__ Tin, const ushort_t* __restrict__ Tcomb,
    const float* __restrict__ b_in, const float* __restrict__ bcomb,
    ushort_t* __restrict__ vproj, float* __restrict__ offlog)
{
    __shared__ ushort_t As[128 * 32];
    __shared__ ushort_t Bs[128 * 32];
    const int bm0 = blockIdx.x * 128;
    const int y = blockIdx.y;
    if (y < 2)
        gemm_tile_core(vbf, Tin, b_in, vproj, true, M_TOT, 256, bm0, y * 128, 256, As, Bs);
    else
        gemm_tile_core(qbf, Tcomb, bcomb, offlog, false, M_TOT, 384, bm0, (y - 2) * 128, 256, As, Bs);
}

__global__ __launch_bounds__(256) void gemm_out_kernel(
    const ushort_t* __restrict__ mid, const ushort_t* __restrict__ Tout,
    const float* __restrict__ b_out, float* __restrict__ out)
{
    __shared__ ushort_t As[128 * 32];
    __shared__ ushort_t Bs[128 * 32];
    gemm_tile_core(mid, Tout, b_out, out, false, M_TOT, 256,
                   blockIdx.x * 128, blockIdx.y * 128, 256, As, Bs);
}

// =====================================================================
// Sampling kernel v6: wave-per-query, ZERO block barriers.
//  - 256 threads = 4 independent waves, one query each.
//  - offlog/p read directly from global (coalesced), no LDS staging.
//  - softmax via __shfl_xor over 16-lane head groups + v_rcp.
//  - division eliminated: x = px*W + ox - 0.5 (algebraic fusion).
//  - (w, byte_idx) handoff through wave-local LDS, XOR-swizzled so
//    phase-2 b128 reads are <=2-way bank conflicts.
//  - gathers: uniform base + 32-bit byte voffset -> saddr form.
//  - __launch_bounds__(256,8): VGPR<=64 -> up to 32 waves/CU.
// =====================================================================
#define ACC4(W, g) \
    ax = fmaf(W, __uint_as_float(g.x << 16), ax);          \
    ay = fmaf(W, __uint_as_float(g.x & 0xffff0000u), ay);  \
    az = fmaf(W, __uint_as_float(g.y << 16), az);          \
    aw = fmaf(W, __uint_as_float(g.y & 0xffff0000u), aw);

__global__ __launch_bounds__(256, 8) void msda_sample_kernel(
    const ushort_t* __restrict__ vproj, const float* __restrict__ offlog,
    const float* __restrict__ p, ushort_t* __restrict__ mid)
{
    __shared__ int s_buf[4096];          // 4 waves x 1024 ints (4 KB/wave)

    const int tid = threadIdx.x;
    const int wv  = tid >> 6;            // wave id 0..3
    const int l   = tid & 63;
    const int nq  = blockIdx.x * 4 + wv;
    const int nb  = (nq >= QN) ? 1 : 0;

    // ---- phase 1: per-lane tasks j0=l (heads 0..3), j1=l+64 (heads 4..7)
    const size_t orow = (size_t)nq * 384;
    const float2 off0 = *(const float2*)&offlog[orow + 2 * l];
    const float2 off1 = *(const float2*)&offlog[orow + 128 + 2 * l];
    const float  lg0  = offlog[orow + 256 + l];
    const float  lg1  = offlog[orow + 320 + l];
    const int    lvl  = (l >> 2) & 3;
    const float2 pl   = *(const float2*)&p[(size_t)nq * 8 + lvl * 2];

    // softmax over 16-lane head groups (two heads per lane, same group)
    float m0 = lg0, m1 = lg1;
    #pragma unroll
    for (int m = 8; m; m >>= 1) {
        m0 = fmaxf(m0, __shfl_xor(m0, m));
        m1 = fmaxf(m1, __shfl_xor(m1, m));
    }
    const float e0 = __expf(lg0 - m0);
    const float e1 = __expf(lg1 - m1);
    float s0 = e0, s1 = e1;
    #pragma unroll
    for (int m = 8; m; m >>= 1) {
        s0 += __shfl_xor(s0, m);
        s1 += __shfl_xor(s1, m);
    }
    const float wt0 = e0 * __builtin_amdgcn_rcpf(s0);
    const float wt1 = e1 * __builtin_amdgcn_rcpf(s1);

    const int   Wl    = 96 >> lvl;                     // H == W per level
    const float fW    = (float)Wl;
    const int   st    = 12288 - (12288 >> (2 * lvl));  // level start pixel
    const int   h4    = l >> 4;
    const int   baseb = nb * (HW_TOT * 512) + st * 512; // byte offsets
    const int   sw    = h4 << 3;                        // XOR swizzle (bits 3,4)
    const int   wbase = wv * 1024 + l * 8;

    #pragma unroll
    for (int set = 0; set < 2; ++set) {
        const float ox = set ? off1.x : off0.x;
        const float oy = set ? off1.y : off0.y;
        const float wt = set ? wt1 : wt0;
        const int   h  = set ? (h4 + 4) : h4;

        const float x  = fmaf(pl.x, fW, ox) - 0.5f;    // px*W + ox - 0.5
        const float y  = fmaf(pl.y, fW, oy) - 0.5f;
        const float xf = floorf(x), yf = floorf(y);
        const float dx = x - xf,    dy = y - yf;
        const int   x0 = (int)xf,   y0 = (int)yf;
        const bool vx0 = (unsigned)x0       < (unsigned)Wl;
        const bool vx1 = (unsigned)(x0 + 1) < (unsigned)Wl;
        const bool vy0 = (unsigned)y0       < (unsigned)Wl;
        const bool vy1 = (unsigned)(y0 + 1) < (unsigned)Wl;

        const int b00 = baseb + (y0 * Wl + x0) * 512 + h * 64;
        const int b01 = b00 + 512;
        const int b10 = b00 + (Wl << 9);
        const int b11 = b10 + 512;

        const float wy0f = wt * (1.0f - dy), wy1f = wt * dy;
        const float w00 = (vx0 && vy0) ? (1.0f - dx) * wy0f : 0.0f;
        const float w01 = (vx1 && vy0) ? dx * wy0f          : 0.0f;
        const float w10 = (vx0 && vy1) ? (1.0f - dx) * wy1f : 0.0f;
        const float w11 = (vx1 && vy1) ? dx * wy1f          : 0.0f;
        const int   i00 = (vx0 && vy0) ? b00 : 0;
        const int   i01 = (vx1 && vy0) ? b01 : 0;
        const int   i10 = (vx0 && vy1) ? b10 : 0;
        const int   i11 = (vx1 && vy1) ? b11 : 0;

        const int o = (wbase + set * 512) ^ sw;
        *(int4*)&s_buf[o]     = (int4){__float_as_int(w00), i00, __float_as_int(w01), i01};
        *(int4*)&s_buf[o + 4] = (int4){__float_as_int(w10), i10, __float_as_int(w11), i11};
    }

    // wave-local LDS handoff: DS ops are in-order per wave; just drain
    // lgkm and fence the compiler. No s_barrier — waves are independent.
    __builtin_amdgcn_wave_barrier();
    asm volatile("s_waitcnt lgkmcnt(0)" ::: "memory");
    __builtin_amdgcn_wave_barrier();

    // ---- phase 2: lane = h*8 + c4; 16 tasks x 4 corners, 4 channels/lane
    const int h   = l >> 3;
    const int c4  = l & 7;
    const int rb  = wv * 1024 + (h >> 2) * 512 + (h & 3) * 128;
    const int sw2 = (h & 3) << 3;
    const char* __restrict__ vb = (const char*)vproj;

    float ax = 0.f, ay = 0.f, az = 0.f, aw = 0.f;
    #pragma unroll 2
    for (int t = 0; t < 16; ++t) {
        const int o = rb + ((t * 8) ^ sw2);
        const int4 cA = *(const int4*)&s_buf[o];
        const int4 cB = *(const int4*)&s_buf[o + 4];
        const uint2 g0 = *(const uint2*)(vb + (unsigned)(cA.y + c4 * 8));
        const uint2 g1 = *(const uint2*)(vb + (unsigned)(cA.w + c4 * 8));
        const uint2 g2 = *(const uint2*)(vb + (unsigned)(cB.y + c4 * 8));
        const uint2 g3 = *(const uint2*)(vb + (unsigned)(cB.w + c4 * 8));
        const float W0 = __int_as_float(cA.x), W1 = __int_as_float(cA.z);
        const float W2 = __int_as_float(cB.x), W3 = __int_as_float(cB.z);
        ACC4(W0, g0);
        ACC4(W1, g1);
        ACC4(W2, g2);
        ACC4(W3, g3);
    }

    ushort_t mv[4] = {f2bf(ax), f2bf(ay), f2bf(az), f2bf(aw)};
    *(uint2*)&mid[(size_t)nq * 256 + l * 4] = *(uint2*)mv;
}

// =====================================================================
extern "C" void kernel_launch(void* const* d_in, const int* in_sizes, int n_in,
                              void* d_out, int out_size, void* d_ws, size_t ws_size,
                              hipStream_t stream)
{
    const float* q      = (const float*)d_in[0];
    const float* p      = (const float*)d_in[1];
    const float* v      = (const float*)d_in[2];
    const float* W_off  = (const float*)d_in[3];
    const float* b_off  = (const float*)d_in[4];
    const float* W_attn = (const float*)d_in[5];
    const float* b_attn = (const float*)d_in[6];
    const float* W_in   = (const float*)d_in[7];
    const float* b_in   = (const float*)d_in[8];
    const float* W_out  = (const float*)d_in[9];
    const float* b_out  = (const float*)d_in[10];
    float* out = (float*)d_out;

    const int M = M_TOT;                            // 24480

    // workspace layout (mid aliases vbf -- vbf dead after proj GEMM)
    ushort_t* vproj  = (ushort_t*)d_ws;                          // M*256 bf16
    float*    offlog = (float*)(vproj + (size_t)M * 256);        // M*384 f32
    ushort_t* vbf    = (ushort_t*)(offlog + (size_t)M * 384);    // M*256 bf16
    ushort_t* mid    = vbf;                                      // alias
    ushort_t* qbf    = vbf + (size_t)M * 256;                    // M*256 bf16
    ushort_t* Tin    = qbf + (size_t)M * 256;
    ushort_t* Tcomb  = Tin + 256 * 256;
    ushort_t* Tout   = Tcomb + 384 * 256;
    float*    bcomb  = (float*)(Tout + 256 * 256);

    // 0a) v,q -> bf16
    convert_qv_kernel<<<dim3(6120), 256, 0, stream>>>(v, q, vbf, qbf);
    // 0b) weights -> transposed bf16 (+ fused off/attn weight & bias)
    prep_weights_kernel<<<dim3(384, 1, 3), 256, 0, stream>>>(
        W_in, W_off, W_attn, W_out, b_off, b_attn, Tin, Tcomb, Tout, bcomb);

    // 1+2+3) fused projection GEMMs (m97-style)
    gemm_proj_kernel<<<dim3(192, 5), 256, 0, stream>>>(
        vbf, qbf, Tin, Tcomb, b_in, bcomb, vproj, offlog);
    // 4) softmax + bilinear sampling -> bf16 mid (wave-per-query)
    msda_sample_kernel<<<dim3(M / 4), 256, 0, stream>>>(vproj, offlog, p, mid);
    // 5) out = mid @ W_out + b_out
    gemm_out_kernel<<<dim3(192, 2), 256, 0, stream>>>(mid, Tout, b_out, out);
}

// Round 4
// 188.672 us; speedup vs baseline: 1.1014x; 1.0458x over previous
//
#include <hip/hip_runtime.h>
#include <hip/hip_bf16.h>
#include <math.h>

// ---- problem constants (structural, from the reference) ----
#define NB      2
#define QN      12240
#define HW_TOT  12240
#define DIMS    256
#define HEADS   8
#define CH      32
#define LEVELS  4
#define POINTS  4
#define M_TOT   (NB * QN)        // 24480

typedef unsigned short ushort_t;
typedef __attribute__((ext_vector_type(8))) short short8;
typedef __attribute__((ext_vector_type(4))) float floatx4;

__device__ __forceinline__ ushort_t f2bf(float f) {
    __hip_bfloat16 h = __float2bfloat16(f);
    return *reinterpret_cast<ushort_t*>(&h);
}

// =====================================================================
// Elementwise fp32 -> bf16 for v and q (one pass, 8 elems/thread).
// =====================================================================
__global__ __launch_bounds__(256) void convert_qv_kernel(
    const float* __restrict__ v, const float* __restrict__ q,
    ushort_t* __restrict__ vbf, ushort_t* __restrict__ qbf)
{
    const size_t i = ((size_t)blockIdx.x * 256 + threadIdx.x) * 8;
    const size_t half = (size_t)M_TOT * DIMS;
    const float* src; ushort_t* dst; size_t off;
    if (i < half) { src = v; dst = vbf; off = i; }
    else          { src = q; dst = qbf; off = i - half; }
    const float4 a = *(const float4*)&src[off];
    const float4 b = *(const float4*)&src[off + 4];
    ushort_t t[8] = {f2bf(a.x), f2bf(a.y), f2bf(a.z), f2bf(a.w),
                     f2bf(b.x), f2bf(b.y), f2bf(b.z), f2bf(b.w)};
    *(int4*)&dst[off] = *(int4*)t;
}

// =====================================================================
// Weights -> transposed bf16 (WT[n][k]); z=1 also builds the fused
// off+attn weight [384][256] and its combined bias.  z=0 additionally
// zeroes the 128B pad after vproj (the sampler's paired-corner gather
// may read <=64B past vproj's end with weight 0 -- the pad guarantees
// those bytes decode to bf16 zeros, never Inf/NaN).
// =====================================================================
__global__ __launch_bounds__(256) void prep_weights_kernel(
    const float* __restrict__ W_in, const float* __restrict__ W_off,
    const float* __restrict__ W_attn, const float* __restrict__ W_out,
    const float* __restrict__ b_off, const float* __restrict__ b_attn,
    ushort_t* __restrict__ Tin, ushort_t* __restrict__ Tcomb,
    ushort_t* __restrict__ Tout, float* __restrict__ bcomb,
    int* __restrict__ vpad)
{
    const int z  = blockIdx.z;
    const int gi = blockIdx.x * 256 + threadIdx.x;
    if (z == 0 && gi < 32) vpad[gi] = 0;          // 128B zero pad
    if (z == 1 && gi < 384)
        bcomb[gi] = (gi < 256) ? b_off[gi] : b_attn[gi - 256];
    const int Nw = (z == 1) ? 384 : 256;
    if (gi >= Nw * 256) return;
    const int k = gi & 255;       // coalesced write along k
    const int n = gi >> 8;
    float val; ushort_t* T;
    if (z == 0)      { val = W_in[k * 256 + n];  T = Tin;  }
    else if (z == 1) { val = (n < 256) ? W_off[k * 256 + n]
                                       : W_attn[k * 128 + (n - 256)]; T = Tcomb; }
    else             { val = W_out[k * 256 + n]; T = Tout; }
    T[n * 256 + k] = f2bf(val);
}

// =====================================================================
// m97-style bf16 MFMA GEMM core: C[M,Nc] = A[M,K] @ BT[Nc,K]^T + bias.
// c_bf16 path writes HEAD-MAJOR vproj: [head][row][32ch]
// (element (h,row,c) at ((h*M + row)*32 + c)) so the sampler's two
// x-adjacent corners are adjacent 64B chunks sharing a 128B line.
// =====================================================================
__device__ __forceinline__ void gemm_tile_core(
    const ushort_t* __restrict__ A, const ushort_t* __restrict__ BT,
    const float* __restrict__ bias, void* __restrict__ C, bool c_bf16,
    int M, int Nc, int bm0, int bn0, int K,
    ushort_t* As, ushort_t* Bs)
{
    const int tid  = threadIdx.x;
    const int wave = tid >> 6;
    const int lane = tid & 63;
    const int quad = lane >> 4;
    const int l16  = lane & 15;
    const int wm   = (wave >> 1) * 64;
    const int wn   = (wave & 1) * 64;

    const int off0 = tid * 16;
    const int row0 = off0 >> 6;
    const int kc0  = (off0 & 63) >> 1;

    int ar0 = bm0 + row0;      if (ar0 > M - 1) ar0 = M - 1;
    int ar1 = bm0 + row0 + 64; if (ar1 > M - 1) ar1 = M - 1;

    const ushort_t* ga0 = A  + (size_t)ar0 * K + kc0;
    const ushort_t* ga1 = A  + (size_t)ar1 * K + kc0;
    const ushort_t* gb0 = BT + (size_t)(bn0 + row0) * K + kc0;
    const ushort_t* gb1 = BT + (size_t)(bn0 + row0 + 64) * K + kc0;

    ushort_t* lA0 = As + wave * 512;
    ushort_t* lA1 = As + wave * 512 + 2048;
    ushort_t* lB0 = Bs + wave * 512;
    ushort_t* lB1 = Bs + wave * 512 + 2048;

    floatx4 acc[4][4];
    #pragma unroll
    for (int i = 0; i < 4; ++i)
        #pragma unroll
        for (int j = 0; j < 4; ++j)
            acc[i][j] = (floatx4){0.f, 0.f, 0.f, 0.f};

    for (int kk = 0; kk < K; kk += 32) {
        __builtin_amdgcn_global_load_lds(
            (const __attribute__((address_space(1))) void*)(ga0 + kk),
            (__attribute__((address_space(3))) void*)lA0, 16, 0, 0);
        __builtin_amdgcn_global_load_lds(
            (const __attribute__((address_space(1))) void*)(ga1 + kk),
            (__attribute__((address_space(3))) void*)lA1, 16, 0, 0);
        __builtin_amdgcn_global_load_lds(
            (const __attribute__((address_space(1))) void*)(gb0 + kk),
            (__attribute__((address_space(3))) void*)lB0, 16, 0, 0);
        __builtin_amdgcn_global_load_lds(
            (const __attribute__((address_space(1))) void*)(gb1 + kk),
            (__attribute__((address_space(3))) void*)lB1, 16, 0, 0);
        __syncthreads();

        short8 af[4], bfr[4];
        #pragma unroll
        for (int mt = 0; mt < 4; ++mt)
            af[mt] = *(const short8*)&As[(wm + mt * 16 + l16) * 32 + quad * 8];
        #pragma unroll
        for (int nt = 0; nt < 4; ++nt)
            bfr[nt] = *(const short8*)&Bs[(wn + nt * 16 + l16) * 32 + quad * 8];
        #pragma unroll
        for (int mt = 0; mt < 4; ++mt)
            #pragma unroll
            for (int nt = 0; nt < 4; ++nt)
                acc[mt][nt] = __builtin_amdgcn_mfma_f32_16x16x32_bf16(
                    af[mt], bfr[nt], acc[mt][nt], 0, 0, 0);
        __syncthreads();
    }

    #pragma unroll
    for (int mt = 0; mt < 4; ++mt) {
        #pragma unroll
        for (int j = 0; j < 4; ++j) {
            const int row = bm0 + wm + mt * 16 + quad * 4 + j;
            if (row >= M) continue;
            #pragma unroll
            for (int nt = 0; nt < 4; ++nt) {
                const int col = bn0 + wn + nt * 16 + l16;
                const float val = acc[mt][nt][j] + bias[col];
                if (c_bf16) {
                    // head-major: ((h*M + row)*32 + ch)
                    const size_t idx = (((size_t)(col >> 5) * M + row) << 5) + (col & 31);
                    ((ushort_t*)C)[idx] = f2bf(val);
                } else {
                    ((float*)C)[(size_t)row * Nc + col] = val;
                }
            }
        }
    }
}

__global__ __launch_bounds__(256) void gemm_proj_kernel(
    const ushort_t* __restrict__ vbf, const ushort_t* __restrict__ qbf,
    const ushort_t* __restrict__ Tin, const ushort_t* __restrict__ Tcomb,
    const float* __restrict__ b_in, const float* __restrict__ bcomb,
    ushort_t* __restrict__ vproj, float* __restrict__ offlog)
{
    __shared__ ushort_t As[128 * 32];
    __shared__ ushort_t Bs[128 * 32];
    const int bm0 = blockIdx.x * 128;
    const int y = blockIdx.y;
    if (y < 2)
        gemm_tile_core(vbf, Tin, b_in, vproj, true, M_TOT, 256, bm0, y * 128, 256, As, Bs);
    else
        gemm_tile_core(qbf, Tcomb, bcomb, offlog, false, M_TOT, 384, bm0, (y - 2) * 128, 256, As, Bs);
}

__global__ __launch_bounds__(256) void gemm_out_kernel(
    const ushort_t* __restrict__ mid, const ushort_t* __restrict__ Tout,
    const float* __restrict__ b_out, float* __restrict__ out)
{
    __shared__ ushort_t As[128 * 32];
    __shared__ ushort_t Bs[128 * 32];
    gemm_tile_core(mid, Tout, b_out, out, false, M_TOT, 256,
                   blockIdx.x * 128, blockIdx.y * 128, 256, As, Bs);
}

// =====================================================================
// Sampling kernel v7c: wave-per-query, paired-corner 128B gathers.
//  - vproj is head-major: pixel-head chunk = 64B; x and x+1 chunks are
//    contiguous -> one dwordx4 gather (8 lanes x 16B = 128B) covers
//    BOTH x-corners of a bilinear row.  32 gathers/wave (was 64).
//  - lanes 0-3 of each 8-lane head group take the left-corner weight,
//    lanes 4-7 the right; one shfl_xor(,4) at the end folds the pair.
//  - OOB corners: weight 0; pair base always a VALID pixel index.
//    The right chunk of the very last pixel (lin = 8*M_TOT-1) reads
//    64B past vproj into a ZEROED 128B pad (bf16 zeros, weight 0).
//    (R2 bug: clamping lin shifted the pair base -> wrong left corner.
//     R3 bug: unpadded overread hit offlog bytes decoding to Inf/NaN;
//     0 * Inf = NaN poisoned the accumulator.)
//  - phase-1 -> phase-2 handoff via XOR-swizzled wave-local LDS
//    (writes bank-even, reads <=2-way).  No block barriers.
// =====================================================================
#define LO32(u) __uint_as_float((u) << 16)
#define HI32(u) __uint_as_float((u) & 0xffff0000u)
#define ACC8(W, g) \
    a0 = fmaf(W, LO32(g.x), a0);  a1 = fmaf(W, HI32(g.x), a1); \
    a2 = fmaf(W, LO32(g.y), a2);  a3 = fmaf(W, HI32(g.y), a3); \
    a4 = fmaf(W, LO32(g.z), a4);  a5 = fmaf(W, HI32(g.z), a5); \
    a6 = fmaf(W, LO32(g.w), a6);  a7 = fmaf(W, HI32(g.w), a7);

__global__ __launch_bounds__(256, 8) void msda_sample_kernel(
    const ushort_t* __restrict__ vproj, const float* __restrict__ offlog,
    const float* __restrict__ p, ushort_t* __restrict__ mid)
{
    __shared__ int s_buf[4096];          // 4 waves x 1024 ints (4 KB/wave)

    const int tid = threadIdx.x;
    const int wv  = tid >> 6;            // wave id 0..3
    const int l   = tid & 63;
    const int nq  = blockIdx.x * 4 + wv;
    const int nb  = (nq >= QN) ? 1 : 0;
    const int wbase = wv * 1024;         // int units

    // ---- phase 1: per-lane samples j0=l (heads 0..3), j1=l+64 (heads 4..7)
    const size_t orow = (size_t)nq * 384;
    const float2 off0 = *(const float2*)&offlog[orow + 2 * l];
    const float2 off1 = *(const float2*)&offlog[orow + 128 + 2 * l];
    const float  lg0  = offlog[orow + 256 + l];
    const float  lg1  = offlog[orow + 320 + l];
    const int    lvl  = (l >> 2) & 3;
    const float2 pl   = *(const float2*)&p[(size_t)nq * 8 + lvl * 2];

    // softmax over 16-lane head groups (two heads per lane, same group)
    float m0 = lg0, m1 = lg1;
    #pragma unroll
    for (int m = 8; m; m >>= 1) {
        m0 = fmaxf(m0, __shfl_xor(m0, m));
        m1 = fmaxf(m1, __shfl_xor(m1, m));
    }
    const float e0 = __expf(lg0 - m0);
    const float e1 = __expf(lg1 - m1);
    float s0 = e0, s1 = e1;
    #pragma unroll
    for (int m = 8; m; m >>= 1) {
        s0 += __shfl_xor(s0, m);
        s1 += __shfl_xor(s1, m);
    }
    const float wt0 = e0 * __builtin_amdgcn_rcpf(s0);
    const float wt1 = e1 * __builtin_amdgcn_rcpf(s1);

    const int   Wl  = 96 >> lvl;                     // H == W per level
    const float fW  = (float)Wl;
    const int   st  = 12288 - (12288 >> (2 * lvl));  // level start pixel
    const int   h4  = l >> 4;

    #pragma unroll
    for (int set = 0; set < 2; ++set) {
        const float ox = set ? off1.x : off0.x;
        const float oy = set ? off1.y : off0.y;
        const float wt = set ? wt1 : wt0;
        const int   h  = set ? (h4 + 4) : h4;

        const float x  = fmaf(pl.x, fW, ox) - 0.5f;  // px*W + ox - 0.5
        const float y  = fmaf(pl.y, fW, oy) - 0.5f;
        const float xf = floorf(x), yf = floorf(y);
        const float dx = x - xf,    dy = y - yf;
        const int   x0 = (int)xf,   y0 = (int)yf;
        const bool vxl = (unsigned)x0       < (unsigned)Wl;
        const bool vxr = (unsigned)(x0 + 1) < (unsigned)Wl;
        const bool vy0 = (unsigned)y0       < (unsigned)Wl;
        const bool vy1 = (unsigned)(y0 + 1) < (unsigned)Wl;

        // left/right corner weights by memory position (handles x0 == -1)
        const float wxl = vxl ? (1.0f - dx) : (vxr ? dx : 0.0f);
        const float wxr = (vxl && vxr) ? dx : 0.0f;
        const int   xb  = vxl ? x0 : 0;

        const float wy0f = wt * (1.0f - dy), wy1f = wt * dy;
        const float w_l0 = vy0 ? wxl * wy0f : 0.0f;
        const float w_r0 = vy0 ? wxr * wy0f : 0.0f;
        const float w_l1 = vy1 ? wxl * wy1f : 0.0f;
        const float w_r1 = vy1 ? wxr * wy1f : 0.0f;

        int yc0 = y0;     if (yc0 < 0) yc0 = 0; if (yc0 > Wl - 1) yc0 = Wl - 1;
        int yc1 = y0 + 1; if (yc1 < 0) yc1 = 0; if (yc1 > Wl - 1) yc1 = Wl - 1;

        const int rowb = h * M_TOT + nb * HW_TOT + st + xb;
        const int lin0 = rowb + yc0 * Wl;   // always a valid pixel-head index
        const int lin1 = rowb + yc1 * Wl;   // (right chunk of the final pixel
                                            //  reads the zeroed pad, weight 0)

        // swizzled store: a in int units, XOR bits 2-3 with bits 8-9
        const int a  = l * 16 + set * 8;
        const int ph = (a ^ (((a >> 8) & 3) << 2)) + wbase;
        *(int4*)&s_buf[ph] = (int4){lin0 << 6, __float_as_int(w_l0),
                                    __float_as_int(w_r0), lin1 << 6};
        *(int2*)&s_buf[ph ^ 4] = (int2){__float_as_int(w_l1), __float_as_int(w_r1)};
    }

    // wave-local LDS handoff: DS ops are in-order per wave; drain lgkm
    // and fence the compiler. No s_barrier — waves are independent.
    __builtin_amdgcn_wave_barrier();
    asm volatile("s_waitcnt lgkmcnt(0)" ::: "memory");
    __builtin_amdgcn_wave_barrier();

    // ---- phase 2: lane = h*8 + c; gathers 16B (8 ch), 2 rows/sample
    const int  h    = l >> 3;
    const int  c16  = (l & 7) * 16;                  // byte offset in 128B pair
    const bool hicn = (l & 4) != 0;                  // right-corner lanes
    const int  rbas = (h & 3) * 256 + (h >> 2) * 8;  // a = (h&3)*256 + t*16 + s*8
    const char* __restrict__ vb = (const char*)vproj;

    float a0 = 0.f, a1 = 0.f, a2 = 0.f, a3 = 0.f;
    float a4 = 0.f, a5 = 0.f, a6 = 0.f, a7 = 0.f;

    #pragma unroll 2
    for (int t = 0; t < 16; ++t) {
        const int ia = rbas + t * 16;
        const int ph = (ia ^ (((ia >> 8) & 3) << 2)) + wbase;
        const int4 cA = *(const int4*)&s_buf[ph];     // {b0, wl0, wr0, b1}
        const int2 cB = *(const int2*)&s_buf[ph ^ 4]; // {wl1, wr1}
        const uint4 g0 = *(const uint4*)(vb + (unsigned)(cA.x + c16));
        const uint4 g1 = *(const uint4*)(vb + (unsigned)(cA.w + c16));
        const float w0 = hicn ? __int_as_float(cA.z) : __int_as_float(cA.y);
        const float w1 = hicn ? __int_as_float(cB.y) : __int_as_float(cB.x);
        ACC8(w0, g0);
        ACC8(w1, g1);
    }

    // fold left/right corner partials across the lane^4 pair
    a0 += __shfl_xor(a0, 4);  a1 += __shfl_xor(a1, 4);
    a2 += __shfl_xor(a2, 4);  a3 += __shfl_xor(a3, 4);
    a4 += __shfl_xor(a4, 4);  a5 += __shfl_xor(a5, 4);
    a6 += __shfl_xor(a6, 4);  a7 += __shfl_xor(a7, 4);

    // lane writes 4 of its 8 channels: lo half (lanes 0-3) / hi half (4-7)
    const float o0 = hicn ? a4 : a0;
    const float o1 = hicn ? a5 : a1;
    const float o2 = hicn ? a6 : a2;
    const float o3 = hicn ? a7 : a3;
    ushort_t mv[4] = {f2bf(o0), f2bf(o1), f2bf(o2), f2bf(o3)};
    const int col = h * 32 + (l & 3) * 8 + (l & 4);
    *(uint2*)&mid[(size_t)nq * 256 + col] = *(uint2*)mv;
}

// =====================================================================
extern "C" void kernel_launch(void* const* d_in, const int* in_sizes, int n_in,
                              void* d_out, int out_size, void* d_ws, size_t ws_size,
                              hipStream_t stream)
{
    const float* q      = (const float*)d_in[0];
    const float* p      = (const float*)d_in[1];
    const float* v      = (const float*)d_in[2];
    const float* W_off  = (const float*)d_in[3];
    const float* b_off  = (const float*)d_in[4];
    const float* W_attn = (const float*)d_in[5];
    const float* b_attn = (const float*)d_in[6];
    const float* W_in   = (const float*)d_in[7];
    const float* b_in   = (const float*)d_in[8];
    const float* W_out  = (const float*)d_in[9];
    const float* b_out  = (const float*)d_in[10];
    float* out = (float*)d_out;

    const int M = M_TOT;                            // 24480

    // workspace layout (mid aliases vbf -- vbf dead after proj GEMM).
    // vproj is followed by a 128B ZEROED pad (sampler overread safety).
    ushort_t* vproj  = (ushort_t*)d_ws;                          // M*256 bf16 (head-major)
    ushort_t* vpad   = vproj + (size_t)M * 256;                  // 64 ushort = 128B zero pad
    float*    offlog = (float*)(vpad + 64);                      // M*384 f32
    ushort_t* vbf    = (ushort_t*)(offlog + (size_t)M * 384);    // M*256 bf16
    ushort_t* mid    = vbf;                                      // alias
    ushort_t* qbf    = vbf + (size_t)M * 256;                    // M*256 bf16
    ushort_t* Tin    = qbf + (size_t)M * 256;
    ushort_t* Tcomb  = Tin + 256 * 256;
    ushort_t* Tout   = Tcomb + 384 * 256;
    float*    bcomb  = (float*)(Tout + 256 * 256);

    // 0a) v,q -> bf16
    convert_qv_kernel<<<dim3(6120), 256, 0, stream>>>(v, q, vbf, qbf);
    // 0b) weights -> transposed bf16 (+ fused off/attn weight & bias + pad zero)
    prep_weights_kernel<<<dim3(384, 1, 3), 256, 0, stream>>>(
        W_in, W_off, W_attn, W_out, b_off, b_attn, Tin, Tcomb, Tout, bcomb,
        (int*)vpad);

    // 1+2+3) fused projection GEMMs (m97-style)
    gemm_proj_kernel<<<dim3(192, 5), 256, 0, stream>>>(
        vbf, qbf, Tin, Tcomb, b_in, bcomb, vproj, offlog);
    // 4) softmax + bilinear sampling -> bf16 mid (paired-corner gathers)
    msda_sample_kernel<<<dim3(M / 4), 256, 0, stream>>>(vproj, offlog, p, mid);
    // 5) out = mid @ W_out + b_out
    gemm_out_kernel<<<dim3(192, 2), 256, 0, stream>>>(mid, Tout, b_out, out);
}

// Round 5
// 179.901 us; speedup vs baseline: 1.1551x; 1.0488x over previous
//
#include <hip/hip_runtime.h>
#include <hip/hip_bf16.h>
#include <hip/hip_fp16.h>
#include <math.h>

// ---- problem constants (structural, from the reference) ----
#define NB      2
#define QN      12240
#define HW_TOT  12240
#define DIMS    256
#define HEADS   8
#define CH      32
#define LEVELS  4
#define POINTS  4
#define M_TOT   (NB * QN)        // 24480

typedef unsigned short ushort_t;
typedef __attribute__((ext_vector_type(8))) short short8;
typedef __attribute__((ext_vector_type(4))) float floatx4;

__device__ __forceinline__ ushort_t f2bf(float f) {
    __hip_bfloat16 h = __float2bfloat16(f);
    return *reinterpret_cast<ushort_t*>(&h);
}
__device__ __forceinline__ ushort_t f2h(float f) {
    __half h = __float2half(f);
    return *reinterpret_cast<ushort_t*>(&h);
}

// =====================================================================
// Merged: fp32->bf16 convert for v,q  PLUS  weight transposes/fusion.
// bx < 6120: convert path (8 elems/thread, covers v then q).
// bx >= 6120: prep path (384 blocks) -- Tin/Tout (bi<256), Tcomb (bi<384),
//             bcomb + 128B vproj pad zero (bi==0/1).
// =====================================================================
__global__ __launch_bounds__(256) void convert_prep_kernel(
    const float* __restrict__ v, const float* __restrict__ q,
    ushort_t* __restrict__ vbf, ushort_t* __restrict__ qbf,
    const float* __restrict__ W_in, const float* __restrict__ W_off,
    const float* __restrict__ W_attn, const float* __restrict__ W_out,
    const float* __restrict__ b_off, const float* __restrict__ b_attn,
    ushort_t* __restrict__ Tin, ushort_t* __restrict__ Tcomb,
    ushort_t* __restrict__ Tout, float* __restrict__ bcomb,
    int* __restrict__ vpad)
{
    const int bx  = blockIdx.x;
    const int tid = threadIdx.x;
    if (bx < 6120) {
        const size_t i = ((size_t)bx * 256 + tid) * 8;
        const size_t half = (size_t)M_TOT * DIMS;
        const float* src; ushort_t* dst; size_t off;
        if (i < half) { src = v; dst = vbf; off = i; }
        else          { src = q; dst = qbf; off = i - half; }
        const float4 a = *(const float4*)&src[off];
        const float4 b = *(const float4*)&src[off + 4];
        ushort_t t[8] = {f2bf(a.x), f2bf(a.y), f2bf(a.z), f2bf(a.w),
                         f2bf(b.x), f2bf(b.y), f2bf(b.z), f2bf(b.w)};
        *(int4*)&dst[off] = *(int4*)t;
        return;
    }
    const int bi = bx - 6120;                 // 0..383
    const int gi = bi * 256 + tid;
    if (gi < 32)  vpad[gi] = 0;               // 128B zero pad after vproj
    if (gi < 384) bcomb[gi] = (gi < 256) ? b_off[gi] : b_attn[gi - 256];
    const int k = gi & 255;                   // coalesced write along k
    const int n = gi >> 8;
    if (gi < 65536) {
        Tin[n * 256 + k]  = f2bf(W_in[k * 256 + n]);
        Tout[n * 256 + k] = f2bf(W_out[k * 256 + n]);
    }
    {   // Tcomb: 384 rows
        const float val = (n < 256) ? W_off[k * 256 + n]
                                    : W_attn[k * 128 + (n - 256)];
        Tcomb[n * 256 + k] = f2bf(val);
    }
}

// =====================================================================
// m97-style bf16 MFMA GEMM core: C[M,Nc] = A[M,K] @ BT[Nc,K]^T + bias.
// cmode: 0 = fp32 row-major, 1 = bf16 HEAD-MAJOR ((h*M+row)*32+ch),
//        2 = fp16 row-major (offlog).
// =====================================================================
__device__ __forceinline__ void gemm_tile_core(
    const ushort_t* __restrict__ A, const ushort_t* __restrict__ BT,
    const float* __restrict__ bias, void* __restrict__ C, int cmode,
    int M, int Nc, int bm0, int bn0, int K,
    ushort_t* As, ushort_t* Bs)
{
    const int tid  = threadIdx.x;
    const int wave = tid >> 6;
    const int lane = tid & 63;
    const int quad = lane >> 4;
    const int l16  = lane & 15;
    const int wm   = (wave >> 1) * 64;
    const int wn   = (wave & 1) * 64;

    const int off0 = tid * 16;
    const int row0 = off0 >> 6;
    const int kc0  = (off0 & 63) >> 1;

    int ar0 = bm0 + row0;      if (ar0 > M - 1) ar0 = M - 1;
    int ar1 = bm0 + row0 + 64; if (ar1 > M - 1) ar1 = M - 1;

    const ushort_t* ga0 = A  + (size_t)ar0 * K + kc0;
    const ushort_t* ga1 = A  + (size_t)ar1 * K + kc0;
    const ushort_t* gb0 = BT + (size_t)(bn0 + row0) * K + kc0;
    const ushort_t* gb1 = BT + (size_t)(bn0 + row0 + 64) * K + kc0;

    ushort_t* lA0 = As + wave * 512;
    ushort_t* lA1 = As + wave * 512 + 2048;
    ushort_t* lB0 = Bs + wave * 512;
    ushort_t* lB1 = Bs + wave * 512 + 2048;

    floatx4 acc[4][4];
    #pragma unroll
    for (int i = 0; i < 4; ++i)
        #pragma unroll
        for (int j = 0; j < 4; ++j)
            acc[i][j] = (floatx4){0.f, 0.f, 0.f, 0.f};

    for (int kk = 0; kk < K; kk += 32) {
        __builtin_amdgcn_global_load_lds(
            (const __attribute__((address_space(1))) void*)(ga0 + kk),
            (__attribute__((address_space(3))) void*)lA0, 16, 0, 0);
        __builtin_amdgcn_global_load_lds(
            (const __attribute__((address_space(1))) void*)(ga1 + kk),
            (__attribute__((address_space(3))) void*)lA1, 16, 0, 0);
        __builtin_amdgcn_global_load_lds(
            (const __attribute__((address_space(1))) void*)(gb0 + kk),
            (__attribute__((address_space(3))) void*)lB0, 16, 0, 0);
        __builtin_amdgcn_global_load_lds(
            (const __attribute__((address_space(1))) void*)(gb1 + kk),
            (__attribute__((address_space(3))) void*)lB1, 16, 0, 0);
        __syncthreads();

        short8 af[4], bfr[4];
        #pragma unroll
        for (int mt = 0; mt < 4; ++mt)
            af[mt] = *(const short8*)&As[(wm + mt * 16 + l16) * 32 + quad * 8];
        #pragma unroll
        for (int nt = 0; nt < 4; ++nt)
            bfr[nt] = *(const short8*)&Bs[(wn + nt * 16 + l16) * 32 + quad * 8];
        #pragma unroll
        for (int mt = 0; mt < 4; ++mt)
            #pragma unroll
            for (int nt = 0; nt < 4; ++nt)
                acc[mt][nt] = __builtin_amdgcn_mfma_f32_16x16x32_bf16(
                    af[mt], bfr[nt], acc[mt][nt], 0, 0, 0);
        __syncthreads();
    }

    #pragma unroll
    for (int mt = 0; mt < 4; ++mt) {
        #pragma unroll
        for (int j = 0; j < 4; ++j) {
            const int row = bm0 + wm + mt * 16 + quad * 4 + j;
            if (row >= M) continue;
            #pragma unroll
            for (int nt = 0; nt < 4; ++nt) {
                const int col = bn0 + wn + nt * 16 + l16;
                const float val = acc[mt][nt][j] + bias[col];
                if (cmode == 1) {
                    // head-major: ((h*M + row)*32 + ch)
                    const size_t idx = (((size_t)(col >> 5) * M + row) << 5) + (col & 31);
                    ((ushort_t*)C)[idx] = f2bf(val);
                } else if (cmode == 2) {
                    ((ushort_t*)C)[(size_t)row * Nc + col] = f2h(val);
                } else {
                    ((float*)C)[(size_t)row * Nc + col] = val;
                }
            }
        }
    }
}

__global__ __launch_bounds__(256) void gemm_proj_kernel(
    const ushort_t* __restrict__ vbf, const ushort_t* __restrict__ qbf,
    const ushort_t* __restrict__ Tin, const ushort_t* __restrict__ Tcomb,
    const float* __restrict__ b_in, const float* __restrict__ bcomb,
    ushort_t* __restrict__ vproj, ushort_t* __restrict__ offh)
{
    __shared__ ushort_t As[128 * 32];
    __shared__ ushort_t Bs[128 * 32];
    const int bm0 = blockIdx.x * 128;
    const int y = blockIdx.y;
    if (y < 2)
        gemm_tile_core(vbf, Tin, b_in, vproj, 1, M_TOT, 256, bm0, y * 128, 256, As, Bs);
    else
        gemm_tile_core(qbf, Tcomb, bcomb, offh, 2, M_TOT, 384, bm0, (y - 2) * 128, 256, As, Bs);
}

__global__ __launch_bounds__(256) void gemm_out_kernel(
    const ushort_t* __restrict__ mid, const ushort_t* __restrict__ Tout,
    const float* __restrict__ b_out, float* __restrict__ out)
{
    __shared__ ushort_t As[128 * 32];
    __shared__ ushort_t Bs[128 * 32];
    gemm_tile_core(mid, Tout, b_out, out, 0, M_TOT, 256,
                   blockIdx.x * 128, blockIdx.y * 128, 256, As, Bs);
}

// =====================================================================
// Sampling kernel v8: head-split + XCD locality + fp16 offlog.
//  - block = 4 queries x 4 heads (half).  hh = (blockIdx%8)>>2 so each
//    XCD serves ONE head-half: gather footprint/XCD = 6.25 MB (vs 12.5),
//    better L2 hit rate.  12240 blocks = 8*1530 (divisible by 8).
//  - wave = 1 query x 4 heads.  Phase 1: lane = (h4, lvl, pt); one
//    sample per lane; softmax over 16-lane head groups.
//  - Phase 2: one dwordx4 gather instr covers 4 heads x 2 rows x 128B
//    (8 lanes per (head,row), lanes 0-3 left corner / 4-7 right).
//    Corner fold shfl_xor(4), row fold shfl_xor(8); 4 lanes/head write.
//  - handoff via stride-17-padded int4/int2 LDS arrays (conflict-free
//    mod-128 for both the 64-lane write and the 4-address broadcast).
//  - OOB: weight 0; pair base always valid; last-pixel right chunk
//    reads the ZEROED 128B pad after vproj (bf16 zeros, weight 0).
// =====================================================================
#define LO32(u) __uint_as_float((u) << 16)
#define HI32(u) __uint_as_float((u) & 0xffff0000u)
#define ACC8(W, g) \
    a0 = fmaf(W, LO32(g.x), a0);  a1 = fmaf(W, HI32(g.x), a1); \
    a2 = fmaf(W, LO32(g.y), a2);  a3 = fmaf(W, HI32(g.y), a3); \
    a4 = fmaf(W, LO32(g.z), a4);  a5 = fmaf(W, HI32(g.z), a5); \
    a6 = fmaf(W, LO32(g.w), a6);  a7 = fmaf(W, HI32(g.w), a7);

__global__ __launch_bounds__(256, 8) void msda_sample_kernel(
    const ushort_t* __restrict__ vproj, const ushort_t* __restrict__ offh,
    const float* __restrict__ p, ushort_t* __restrict__ mid)
{
    __shared__ int4 s_main[4][68];       // [wave][h4*17 + s]
    __shared__ int2 s_aux[4][68];

    const int tid = threadIdx.x;
    const int wv  = tid >> 6;            // wave id 0..3
    const int l   = tid & 63;
    const int idx = blockIdx.x;
    const int b8  = idx & 7;             // XCD id (round-robin assumption)
    const int hh  = b8 >> 2;             // head half: XCD 0-3 -> 0, 4-7 -> 1
    const int qg  = (idx >> 3) * 4 + (b8 & 3);
    const int nq  = qg * 4 + wv;
    const int nb  = (nq >= QN) ? 1 : 0;

    // ---- phase 1: lane = sample (h4 = l>>4, lvl = (l>>2)&3, pt = l&3)
    const size_t orow = (size_t)nq * 384;
    const __half2 o2 = *(const __half2*)&offh[orow + hh * 128 + 2 * l];
    const float2  of = __half22float2(o2);
    const float   lg = __half2float(
        *(const __half*)&offh[orow + 256 + hh * 64 + l]);
    const int     lvl = (l >> 2) & 3;
    const float2  pl  = *(const float2*)&p[(size_t)nq * 8 + lvl * 2];

    // softmax over 16-lane head groups
    float mx = lg;
    #pragma unroll
    for (int m = 8; m; m >>= 1) mx = fmaxf(mx, __shfl_xor(mx, m));
    const float e = __expf(lg - mx);
    float ss = e;
    #pragma unroll
    for (int m = 8; m; m >>= 1) ss += __shfl_xor(ss, m);
    const float wt = e * __builtin_amdgcn_rcpf(ss);

    const int   Wl = 96 >> lvl;                     // H == W per level
    const float fW = (float)Wl;
    const int   st = 12288 - (12288 >> (2 * lvl));  // level start pixel
    const int   h4 = l >> 4;
    const int   h  = hh * 4 + h4;                   // global head

    {
        const float x  = fmaf(pl.x, fW, of.x) - 0.5f;
        const float y  = fmaf(pl.y, fW, of.y) - 0.5f;
        const float xf = floorf(x), yf = floorf(y);
        const float dx = x - xf,    dy = y - yf;
        const int   x0 = (int)xf,   y0 = (int)yf;
        const bool vxl = (unsigned)x0       < (unsigned)Wl;
        const bool vxr = (unsigned)(x0 + 1) < (unsigned)Wl;
        const bool vy0 = (unsigned)y0       < (unsigned)Wl;
        const bool vy1 = (unsigned)(y0 + 1) < (unsigned)Wl;

        const float wxl = vxl ? (1.0f - dx) : (vxr ? dx : 0.0f);
        const float wxr = (vxl && vxr) ? dx : 0.0f;
        const int   xb  = vxl ? x0 : 0;

        const float wy0f = wt * (1.0f - dy), wy1f = wt * dy;
        const float w_l0 = vy0 ? wxl * wy0f : 0.0f;
        const float w_r0 = vy0 ? wxr * wy0f : 0.0f;
        const float w_l1 = vy1 ? wxl * wy1f : 0.0f;
        const float w_r1 = vy1 ? wxr * wy1f : 0.0f;

        int yc0 = y0;     if (yc0 < 0) yc0 = 0; if (yc0 > Wl - 1) yc0 = Wl - 1;
        int yc1 = y0 + 1; if (yc1 < 0) yc1 = 0; if (yc1 > Wl - 1) yc1 = Wl - 1;

        const int rowb = h * M_TOT + nb * HW_TOT + st + xb;
        const int lin0 = rowb + yc0 * Wl;   // valid pixel-head index
        const int lin1 = rowb + yc1 * Wl;   // (final pixel's right chunk
                                            //  reads the zeroed pad, w=0)
        const int e17 = h4 * 17 + (l & 15);
        s_main[wv][e17] = (int4){lin0 << 6, __float_as_int(w_l0),
                                 __float_as_int(w_r0), lin1 << 6};
        s_aux[wv][e17]  = (int2){__float_as_int(w_l1), __float_as_int(w_r1)};
    }

    // wave-local LDS handoff: DS ops are in-order per wave; drain lgkm
    // and fence the compiler.  No s_barrier -- waves are independent.
    __builtin_amdgcn_wave_barrier();
    asm volatile("s_waitcnt lgkmcnt(0)" ::: "memory");
    __builtin_amdgcn_wave_barrier();

    // ---- phase 2: lane = (head hg, row r, corner, ch-quad)
    const int hg     = l >> 4;           // head within half
    const int rowr   = (l >> 3) & 1;
    const int corner = (l >> 2) & 1;
    const int c16    = (l & 7) * 16;     // byte offset within 128B pair
    const char* __restrict__ vb = (const char*)vproj;

    float a0 = 0.f, a1 = 0.f, a2 = 0.f, a3 = 0.f;
    float a4 = 0.f, a5 = 0.f, a6 = 0.f, a7 = 0.f;

    #pragma unroll 4
    for (int t = 0; t < 16; ++t) {
        const int  e17 = hg * 17 + t;
        const int4 c   = s_main[wv][e17];   // {b0, wl0, wr0, b1}
        const int2 cb  = s_aux[wv][e17];    // {wl1, wr1}
        const int  base = rowr ? c.w : c.x;
        const float wl  = rowr ? __int_as_float(cb.x) : __int_as_float(c.y);
        const float wr  = rowr ? __int_as_float(cb.y) : __int_as_float(c.z);
        const float w   = corner ? wr : wl;
        const uint4 g   = *(const uint4*)(vb + (unsigned)(base + c16));
        ACC8(w, g);
    }

    // fold corners (bit2) then rows (bit3)
    a0 += __shfl_xor(a0, 4);  a1 += __shfl_xor(a1, 4);
    a2 += __shfl_xor(a2, 4);  a3 += __shfl_xor(a3, 4);
    a4 += __shfl_xor(a4, 4);  a5 += __shfl_xor(a5, 4);
    a6 += __shfl_xor(a6, 4);  a7 += __shfl_xor(a7, 4);
    a0 += __shfl_xor(a0, 8);  a1 += __shfl_xor(a1, 8);
    a2 += __shfl_xor(a2, 8);  a3 += __shfl_xor(a3, 8);
    a4 += __shfl_xor(a4, 8);  a5 += __shfl_xor(a5, 8);
    a6 += __shfl_xor(a6, 8);  a7 += __shfl_xor(a7, 8);

    if ((l & 12) == 0) {                 // 4 writer lanes per head
        ushort_t mv[8] = {f2bf(a0), f2bf(a1), f2bf(a2), f2bf(a3),
                          f2bf(a4), f2bf(a5), f2bf(a6), f2bf(a7)};
        const int col = (hh * 4 + hg) * 32 + (l & 3) * 8;
        *(uint4*)&mid[(size_t)nq * 256 + col] = *(uint4*)mv;
    }
}

// =====================================================================
extern "C" void kernel_launch(void* const* d_in, const int* in_sizes, int n_in,
                              void* d_out, int out_size, void* d_ws, size_t ws_size,
                              hipStream_t stream)
{
    const float* q      = (const float*)d_in[0];
    const float* p      = (const float*)d_in[1];
    const float* v      = (const float*)d_in[2];
    const float* W_off  = (const float*)d_in[3];
    const float* b_off  = (const float*)d_in[4];
    const float* W_attn = (const float*)d_in[5];
    const float* b_attn = (const float*)d_in[6];
    const float* W_in   = (const float*)d_in[7];
    const float* b_in   = (const float*)d_in[8];
    const float* W_out  = (const float*)d_in[9];
    const float* b_out  = (const float*)d_in[10];
    float* out = (float*)d_out;

    const int M = M_TOT;                            // 24480

    // workspace layout (mid aliases vbf -- vbf dead after proj GEMM).
    // vproj is followed by a 128B ZEROED pad (sampler overread safety).
    ushort_t* vproj  = (ushort_t*)d_ws;                          // M*256 bf16 (head-major)
    ushort_t* vpad   = vproj + (size_t)M * 256;                  // 64 ushort = 128B zero pad
    ushort_t* offh   = vpad + 64;                                // M*384 fp16
    ushort_t* vbf    = offh + (size_t)M * 384;                   // M*256 bf16
    ushort_t* mid    = vbf;                                      // alias
    ushort_t* qbf    = vbf + (size_t)M * 256;                    // M*256 bf16
    ushort_t* Tin    = qbf + (size_t)M * 256;
    ushort_t* Tcomb  = Tin + 256 * 256;
    ushort_t* Tout   = Tcomb + 384 * 256;
    float*    bcomb  = (float*)(Tout + 256 * 256);

    // 0) v,q -> bf16  +  weight transposes/fusion + pad zero (merged)
    convert_prep_kernel<<<dim3(6504), 256, 0, stream>>>(
        v, q, vbf, qbf, W_in, W_off, W_attn, W_out, b_off, b_attn,
        Tin, Tcomb, Tout, bcomb, (int*)vpad);

    // 1+2+3) fused projection GEMMs (m97-style); offlog written fp16
    gemm_proj_kernel<<<dim3(192, 5), 256, 0, stream>>>(
        vbf, qbf, Tin, Tcomb, b_in, bcomb, vproj, offh);
    // 4) softmax + bilinear sampling -> bf16 mid (head-split, XCD-local)
    msda_sample_kernel<<<dim3(12240), 256, 0, stream>>>(vproj, offh, p, mid);
    // 5) out = mid @ W_out + b_out
    gemm_out_kernel<<<dim3(192, 2), 256, 0, stream>>>(mid, Tout, b_out, out);
}

// Round 6
// 178.064 us; speedup vs baseline: 1.1671x; 1.0103x over previous
//
#include <hip/hip_runtime.h>
#include <hip/hip_bf16.h>
#include <hip/hip_fp16.h>
#include <math.h>

// ---- problem constants (structural, from the reference) ----
#define NB      2
#define QN      12240
#define HW_TOT  12240
#define DIMS    256
#define HEADS   8
#define CH      32
#define LEVELS  4
#define POINTS  4
#define M_TOT   (NB * QN)        // 24480

typedef unsigned short ushort_t;
typedef __attribute__((ext_vector_type(8))) short short8;
typedef __attribute__((ext_vector_type(4))) float floatx4;

__device__ __forceinline__ ushort_t f2bf(float f) {
    __hip_bfloat16 h = __float2bfloat16(f);
    return *reinterpret_cast<ushort_t*>(&h);
}
__device__ __forceinline__ ushort_t f2h(float f) {
    __half h = __float2half(f);
    return *reinterpret_cast<ushort_t*>(&h);
}

// =====================================================================
// Weights -> transposed bf16 (small, 384 blocks): Tin/Tout (gi<65536),
// Tcomb [384][256], combined bias, and the 128B zero pad after vproj.
// =====================================================================
__global__ __launch_bounds__(256) void prep_weights_kernel(
    const float* __restrict__ W_in, const float* __restrict__ W_off,
    const float* __restrict__ W_attn, const float* __restrict__ W_out,
    const float* __restrict__ b_off, const float* __restrict__ b_attn,
    ushort_t* __restrict__ Tin, ushort_t* __restrict__ Tcomb,
    ushort_t* __restrict__ Tout, float* __restrict__ bcomb,
    int* __restrict__ vpad)
{
    const int gi = blockIdx.x * 256 + threadIdx.x;   // grid = 384 blocks
    if (gi < 32)  vpad[gi] = 0;                      // 128B zero pad
    if (gi < 384) bcomb[gi] = (gi < 256) ? b_off[gi] : b_attn[gi - 256];
    const int k = gi & 255;                          // coalesced along k
    const int n = gi >> 8;
    if (gi < 65536) {
        Tin[n * 256 + k]  = f2bf(W_in[k * 256 + n]);
        Tout[n * 256 + k] = f2bf(W_out[k * 256 + n]);
    }
    const float val = (n < 256) ? W_off[k * 256 + n]
                                : W_attn[k * 128 + (n - 256)];
    Tcomb[n * 256 + k] = f2bf(val);
}

// =====================================================================
// Fused-convert GEMM tile: C = A32[M,256] @ BT[Nc,256]^T + bias, where
// A is RAW FP32 (v or q) converted to bf16 in registers during staging
// (kills the standalone convert kernel + the vbf/qbf round-trip).
// DUAL: two 128-col tiles share one A-pass (32 MFMA per barrier-pair).
// B staged via global_load_lds (already bf16); A via float4 loads ->
// 16 cvt -> 2 ds_write_b128 (linear LDS, same layout as gload_lds).
// CMODE: 1 = bf16 HEAD-MAJOR ((h*M+row)*32+ch), 2 = fp16 row-major.
// =====================================================================
template<int CMODE, bool DUAL>
__device__ __forceinline__ void gemm_fused_tile(
    const float* __restrict__ A32, const ushort_t* __restrict__ BT,
    const float* __restrict__ bias, void* __restrict__ C,
    int M, int Nc, int bm0, int bn0a, int bn0b,
    ushort_t* As, ushort_t* Bs0, ushort_t* Bs1)
{
    const int tid  = threadIdx.x;
    const int wave = tid >> 6;
    const int lane = tid & 63;
    const int quad = lane >> 4;
    const int l16  = lane & 15;
    const int wm   = (wave >> 1) * 64;
    const int wn   = (wave & 1) * 64;

    const int off0 = tid * 16;            // LDS byte offset (linear)
    const int row0 = off0 >> 6;           // 0..63 (64B = 32 bf16/row)
    const int kc0  = (off0 & 63) >> 1;    // element k-offset: 0/8/16/24

    int ar0 = bm0 + row0;      if (ar0 > M - 1) ar0 = M - 1;
    int ar1 = bm0 + row0 + 64; if (ar1 > M - 1) ar1 = M - 1;

    const float*    gA0  = A32 + (size_t)ar0 * 256 + kc0;
    const float*    gA1  = A32 + (size_t)ar1 * 256 + kc0;
    const ushort_t* gb0a = BT + (size_t)(bn0a + row0) * 256 + kc0;
    const ushort_t* gb1a = BT + (size_t)(bn0a + row0 + 64) * 256 + kc0;
    const ushort_t* gb0b = BT + (size_t)(bn0b + row0) * 256 + kc0;
    const ushort_t* gb1b = BT + (size_t)(bn0b + row0 + 64) * 256 + kc0;

    ushort_t* lB0a = Bs0 + wave * 512;
    ushort_t* lB1a = Bs0 + wave * 512 + 2048;
    ushort_t* lB0b = Bs1 + wave * 512;
    ushort_t* lB1b = Bs1 + wave * 512 + 2048;

    floatx4 acc0[4][4], acc1[4][4];
    #pragma unroll
    for (int i = 0; i < 4; ++i)
        #pragma unroll
        for (int j = 0; j < 4; ++j) {
            acc0[i][j] = (floatx4){0.f, 0.f, 0.f, 0.f};
            if (DUAL) acc1[i][j] = (floatx4){0.f, 0.f, 0.f, 0.f};
        }

    for (int kk = 0; kk < 256; kk += 32) {
        // B tiles: async direct-to-LDS (issue first, overlap A staging)
        __builtin_amdgcn_global_load_lds(
            (const __attribute__((address_space(1))) void*)(gb0a + kk),
            (__attribute__((address_space(3))) void*)lB0a, 16, 0, 0);
        __builtin_amdgcn_global_load_lds(
            (const __attribute__((address_space(1))) void*)(gb1a + kk),
            (__attribute__((address_space(3))) void*)lB1a, 16, 0, 0);
        if (DUAL) {
            __builtin_amdgcn_global_load_lds(
                (const __attribute__((address_space(1))) void*)(gb0b + kk),
                (__attribute__((address_space(3))) void*)lB0b, 16, 0, 0);
            __builtin_amdgcn_global_load_lds(
                (const __attribute__((address_space(1))) void*)(gb1b + kk),
                (__attribute__((address_space(3))) void*)lB1b, 16, 0, 0);
        }
        // A: fp32 -> bf16 reg-staged (each thread: 2 rows x 8 elems)
        {
            const float4 a0 = *(const float4*)(gA0 + kk);
            const float4 a1 = *(const float4*)(gA0 + kk + 4);
            const float4 b0 = *(const float4*)(gA1 + kk);
            const float4 b1 = *(const float4*)(gA1 + kk + 4);
            ushort_t t0[8] = {f2bf(a0.x), f2bf(a0.y), f2bf(a0.z), f2bf(a0.w),
                              f2bf(a1.x), f2bf(a1.y), f2bf(a1.z), f2bf(a1.w)};
            ushort_t t1[8] = {f2bf(b0.x), f2bf(b0.y), f2bf(b0.z), f2bf(b0.w),
                              f2bf(b1.x), f2bf(b1.y), f2bf(b1.z), f2bf(b1.w)};
            *(int4*)&As[tid * 8]        = *(int4*)t0;
            *(int4*)&As[tid * 8 + 2048] = *(int4*)t1;
        }
        __syncthreads();

        short8 af[4], bfa[4], bfb[4];
        #pragma unroll
        for (int mt = 0; mt < 4; ++mt)
            af[mt] = *(const short8*)&As[(wm + mt * 16 + l16) * 32 + quad * 8];
        #pragma unroll
        for (int nt = 0; nt < 4; ++nt) {
            bfa[nt] = *(const short8*)&Bs0[(wn + nt * 16 + l16) * 32 + quad * 8];
            if (DUAL)
                bfb[nt] = *(const short8*)&Bs1[(wn + nt * 16 + l16) * 32 + quad * 8];
        }
        #pragma unroll
        for (int mt = 0; mt < 4; ++mt)
            #pragma unroll
            for (int nt = 0; nt < 4; ++nt) {
                acc0[mt][nt] = __builtin_amdgcn_mfma_f32_16x16x32_bf16(
                    af[mt], bfa[nt], acc0[mt][nt], 0, 0, 0);
                if (DUAL)
                    acc1[mt][nt] = __builtin_amdgcn_mfma_f32_16x16x32_bf16(
                        af[mt], bfb[nt], acc1[mt][nt], 0, 0, 0);
            }
        __syncthreads();
    }

    #pragma unroll
    for (int mt = 0; mt < 4; ++mt) {
        #pragma unroll
        for (int j = 0; j < 4; ++j) {
            const int row = bm0 + wm + mt * 16 + quad * 4 + j;
            if (row >= M) continue;
            #pragma unroll
            for (int nt = 0; nt < 4; ++nt) {
                {
                    const int col = bn0a + wn + nt * 16 + l16;
                    const float val = acc0[mt][nt][j] + bias[col];
                    if (CMODE == 1) {
                        const size_t idx = (((size_t)(col >> 5) * M + row) << 5) + (col & 31);
                        ((ushort_t*)C)[idx] = f2bf(val);
                    } else {
                        ((ushort_t*)C)[(size_t)row * Nc + col] = f2h(val);
                    }
                }
                if (DUAL) {
                    const int col = bn0b + wn + nt * 16 + l16;
                    const float val = acc1[mt][nt][j] + bias[col];
                    if (CMODE == 1) {
                        const size_t idx = (((size_t)(col >> 5) * M + row) << 5) + (col & 31);
                        ((ushort_t*)C)[idx] = f2bf(val);
                    } else {
                        ((ushort_t*)C)[(size_t)row * Nc + col] = f2h(val);
                    }
                }
            }
        }
    }
}

__global__ __launch_bounds__(256) void gemm_proj_kernel(
    const float* __restrict__ v, const float* __restrict__ q,
    const ushort_t* __restrict__ Tin, const ushort_t* __restrict__ Tcomb,
    const float* __restrict__ b_in, const float* __restrict__ bcomb,
    ushort_t* __restrict__ vproj, ushort_t* __restrict__ offh)
{
    __shared__ ushort_t As [128 * 32];
    __shared__ ushort_t Bs0[128 * 32];
    __shared__ ushort_t Bs1[128 * 32];
    const int bm0 = blockIdx.x * 128;
    const int y = blockIdx.y;
    if (y == 0)       // vproj = v @ W_in (bf16 head-major), both col-tiles
        gemm_fused_tile<1, true >(v, Tin,   b_in,  vproj, M_TOT, 256, bm0, 0, 128, As, Bs0, Bs1);
    else if (y == 1)  // offh cols 0-255 = q @ Tcomb (fp16)
        gemm_fused_tile<2, true >(q, Tcomb, bcomb, offh,  M_TOT, 384, bm0, 0, 128, As, Bs0, Bs1);
    else              // offh cols 256-383
        gemm_fused_tile<2, false>(q, Tcomb, bcomb, offh,  M_TOT, 384, bm0, 256, 0, As, Bs0, Bs1);
}

// =====================================================================
// m97-style bf16 GEMM for the output projection (unchanged from R5).
// =====================================================================
__device__ __forceinline__ void gemm_tile_core(
    const ushort_t* __restrict__ A, const ushort_t* __restrict__ BT,
    const float* __restrict__ bias, float* __restrict__ C,
    int M, int Nc, int bm0, int bn0, int K,
    ushort_t* As, ushort_t* Bs)
{
    const int tid  = threadIdx.x;
    const int wave = tid >> 6;
    const int lane = tid & 63;
    const int quad = lane >> 4;
    const int l16  = lane & 15;
    const int wm   = (wave >> 1) * 64;
    const int wn   = (wave & 1) * 64;

    const int off0 = tid * 16;
    const int row0 = off0 >> 6;
    const int kc0  = (off0 & 63) >> 1;

    int ar0 = bm0 + row0;      if (ar0 > M - 1) ar0 = M - 1;
    int ar1 = bm0 + row0 + 64; if (ar1 > M - 1) ar1 = M - 1;

    const ushort_t* ga0 = A  + (size_t)ar0 * K + kc0;
    const ushort_t* ga1 = A  + (size_t)ar1 * K + kc0;
    const ushort_t* gb0 = BT + (size_t)(bn0 + row0) * K + kc0;
    const ushort_t* gb1 = BT + (size_t)(bn0 + row0 + 64) * K + kc0;

    ushort_t* lA0 = As + wave * 512;
    ushort_t* lA1 = As + wave * 512 + 2048;
    ushort_t* lB0 = Bs + wave * 512;
    ushort_t* lB1 = Bs + wave * 512 + 2048;

    floatx4 acc[4][4];
    #pragma unroll
    for (int i = 0; i < 4; ++i)
        #pragma unroll
        for (int j = 0; j < 4; ++j)
            acc[i][j] = (floatx4){0.f, 0.f, 0.f, 0.f};

    for (int kk = 0; kk < K; kk += 32) {
        __builtin_amdgcn_global_load_lds(
            (const __attribute__((address_space(1))) void*)(ga0 + kk),
            (__attribute__((address_space(3))) void*)lA0, 16, 0, 0);
        __builtin_amdgcn_global_load_lds(
            (const __attribute__((address_space(1))) void*)(ga1 + kk),
            (__attribute__((address_space(3))) void*)lA1, 16, 0, 0);
        __builtin_amdgcn_global_load_lds(
            (const __attribute__((address_space(1))) void*)(gb0 + kk),
            (__attribute__((address_space(3))) void*)lB0, 16, 0, 0);
        __builtin_amdgcn_global_load_lds(
            (const __attribute__((address_space(1))) void*)(gb1 + kk),
            (__attribute__((address_space(3))) void*)lB1, 16, 0, 0);
        __syncthreads();

        short8 af[4], bfr[4];
        #pragma unroll
        for (int mt = 0; mt < 4; ++mt)
            af[mt] = *(const short8*)&As[(wm + mt * 16 + l16) * 32 + quad * 8];
        #pragma unroll
        for (int nt = 0; nt < 4; ++nt)
            bfr[nt] = *(const short8*)&Bs[(wn + nt * 16 + l16) * 32 + quad * 8];
        #pragma unroll
        for (int mt = 0; mt < 4; ++mt)
            #pragma unroll
            for (int nt = 0; nt < 4; ++nt)
                acc[mt][nt] = __builtin_amdgcn_mfma_f32_16x16x32_bf16(
                    af[mt], bfr[nt], acc[mt][nt], 0, 0, 0);
        __syncthreads();
    }

    #pragma unroll
    for (int mt = 0; mt < 4; ++mt) {
        #pragma unroll
        for (int j = 0; j < 4; ++j) {
            const int row = bm0 + wm + mt * 16 + quad * 4 + j;
            if (row >= M) continue;
            #pragma unroll
            for (int nt = 0; nt < 4; ++nt) {
                const int col = bn0 + wn + nt * 16 + l16;
                C[(size_t)row * Nc + col] = acc[mt][nt][j] + bias[col];
            }
        }
    }
}

__global__ __launch_bounds__(256) void gemm_out_kernel(
    const ushort_t* __restrict__ mid, const ushort_t* __restrict__ Tout,
    const float* __restrict__ b_out, float* __restrict__ out)
{
    __shared__ ushort_t As[128 * 32];
    __shared__ ushort_t Bs[128 * 32];
    gemm_tile_core(mid, Tout, b_out, out, M_TOT, 256,
                   blockIdx.x * 128, blockIdx.y * 128, 256, As, Bs);
}

// =====================================================================
// Sampling kernel v8 (unchanged from R5): head-split + XCD locality +
// fp16 offlog; paired-corner 128B gathers; zeroed-pad overread safety.
// =====================================================================
#define LO32(u) __uint_as_float((u) << 16)
#define HI32(u) __uint_as_float((u) & 0xffff0000u)
#define ACC8(W, g) \
    a0 = fmaf(W, LO32(g.x), a0);  a1 = fmaf(W, HI32(g.x), a1); \
    a2 = fmaf(W, LO32(g.y), a2);  a3 = fmaf(W, HI32(g.y), a3); \
    a4 = fmaf(W, LO32(g.z), a4);  a5 = fmaf(W, HI32(g.z), a5); \
    a6 = fmaf(W, LO32(g.w), a6);  a7 = fmaf(W, HI32(g.w), a7);

__global__ __launch_bounds__(256, 8) void msda_sample_kernel(
    const ushort_t* __restrict__ vproj, const ushort_t* __restrict__ offh,
    const float* __restrict__ p, ushort_t* __restrict__ mid)
{
    __shared__ int4 s_main[4][68];       // [wave][h4*17 + s]
    __shared__ int2 s_aux[4][68];

    const int tid = threadIdx.x;
    const int wv  = tid >> 6;            // wave id 0..3
    const int l   = tid & 63;
    const int idx = blockIdx.x;
    const int b8  = idx & 7;             // XCD id (round-robin assumption)
    const int hh  = b8 >> 2;             // head half: XCD 0-3 -> 0, 4-7 -> 1
    const int qg  = (idx >> 3) * 4 + (b8 & 3);
    const int nq  = qg * 4 + wv;
    const int nb  = (nq >= QN) ? 1 : 0;

    // ---- phase 1: lane = sample (h4 = l>>4, lvl = (l>>2)&3, pt = l&3)
    const size_t orow = (size_t)nq * 384;
    const __half2 o2 = *(const __half2*)&offh[orow + hh * 128 + 2 * l];
    const float2  of = __half22float2(o2);
    const float   lg = __half2float(
        *(const __half*)&offh[orow + 256 + hh * 64 + l]);
    const int     lvl = (l >> 2) & 3;
    const float2  pl  = *(const float2*)&p[(size_t)nq * 8 + lvl * 2];

    // softmax over 16-lane head groups
    float mx = lg;
    #pragma unroll
    for (int m = 8; m; m >>= 1) mx = fmaxf(mx, __shfl_xor(mx, m));
    const float e = __expf(lg - mx);
    float ss = e;
    #pragma unroll
    for (int m = 8; m; m >>= 1) ss += __shfl_xor(ss, m);
    const float wt = e * __builtin_amdgcn_rcpf(ss);

    const int   Wl = 96 >> lvl;                     // H == W per level
    const float fW = (float)Wl;
    const int   st = 12288 - (12288 >> (2 * lvl));  // level start pixel
    const int   h4 = l >> 4;
    const int   h  = hh * 4 + h4;                   // global head

    {
        const float x  = fmaf(pl.x, fW, of.x) - 0.5f;
        const float y  = fmaf(pl.y, fW, of.y) - 0.5f;
        const float xf = floorf(x), yf = floorf(y);
        const float dx = x - xf,    dy = y - yf;
        const int   x0 = (int)xf,   y0 = (int)yf;
        const bool vxl = (unsigned)x0       < (unsigned)Wl;
        const bool vxr = (unsigned)(x0 + 1) < (unsigned)Wl;
        const bool vy0 = (unsigned)y0       < (unsigned)Wl;
        const bool vy1 = (unsigned)(y0 + 1) < (unsigned)Wl;

        const float wxl = vxl ? (1.0f - dx) : (vxr ? dx : 0.0f);
        const float wxr = (vxl && vxr) ? dx : 0.0f;
        const int   xb  = vxl ? x0 : 0;

        const float wy0f = wt * (1.0f - dy), wy1f = wt * dy;
        const float w_l0 = vy0 ? wxl * wy0f : 0.0f;
        const float w_r0 = vy0 ? wxr * wy0f : 0.0f;
        const float w_l1 = vy1 ? wxl * wy1f : 0.0f;
        const float w_r1 = vy1 ? wxr * wy1f : 0.0f;

        int yc0 = y0;     if (yc0 < 0) yc0 = 0; if (yc0 > Wl - 1) yc0 = Wl - 1;
        int yc1 = y0 + 1; if (yc1 < 0) yc1 = 0; if (yc1 > Wl - 1) yc1 = Wl - 1;

        const int rowb = h * M_TOT + nb * HW_TOT + st + xb;
        const int lin0 = rowb + yc0 * Wl;   // valid pixel-head index
        const int lin1 = rowb + yc1 * Wl;   // (final pixel's right chunk
                                            //  reads the zeroed pad, w=0)
        const int e17 = h4 * 17 + (l & 15);
        s_main[wv][e17] = (int4){lin0 << 6, __float_as_int(w_l0),
                                 __float_as_int(w_r0), lin1 << 6};
        s_aux[wv][e17]  = (int2){__float_as_int(w_l1), __float_as_int(w_r1)};
    }

    // wave-local LDS handoff: DS ops are in-order per wave; drain lgkm
    // and fence the compiler.  No s_barrier -- waves are independent.
    __builtin_amdgcn_wave_barrier();
    asm volatile("s_waitcnt lgkmcnt(0)" ::: "memory");
    __builtin_amdgcn_wave_barrier();

    // ---- phase 2: lane = (head hg, row r, corner, ch-quad)
    const int hg     = l >> 4;           // head within half
    const int rowr   = (l >> 3) & 1;
    const int corner = (l >> 2) & 1;
    const int c16    = (l & 7) * 16;     // byte offset within 128B pair
    const char* __restrict__ vb = (const char*)vproj;

    float a0 = 0.f, a1 = 0.f, a2 = 0.f, a3 = 0.f;
    float a4 = 0.f, a5 = 0.f, a6 = 0.f, a7 = 0.f;

    #pragma unroll 4
    for (int t = 0; t < 16; ++t) {
        const int  e17 = hg * 17 + t;
        const int4 c   = s_main[wv][e17];   // {b0, wl0, wr0, b1}
        const int2 cb  = s_aux[wv][e17];    // {wl1, wr1}
        const int  base = rowr ? c.w : c.x;
        const float wl  = rowr ? __int_as_float(cb.x) : __int_as_float(c.y);
        const float wr  = rowr ? __int_as_float(cb.y) : __int_as_float(c.z);
        const float w   = corner ? wr : wl;
        const uint4 g   = *(const uint4*)(vb + (unsigned)(base + c16));
        ACC8(w, g);
    }

    // fold corners (bit2) then rows (bit3)
    a0 += __shfl_xor(a0, 4);  a1 += __shfl_xor(a1, 4);
    a2 += __shfl_xor(a2, 4);  a3 += __shfl_xor(a3, 4);
    a4 += __shfl_xor(a4, 4);  a5 += __shfl_xor(a5, 4);
    a6 += __shfl_xor(a6, 4);  a7 += __shfl_xor(a7, 4);
    a0 += __shfl_xor(a0, 8);  a1 += __shfl_xor(a1, 8);
    a2 += __shfl_xor(a2, 8);  a3 += __shfl_xor(a3, 8);
    a4 += __shfl_xor(a4, 8);  a5 += __shfl_xor(a5, 8);
    a6 += __shfl_xor(a6, 8);  a7 += __shfl_xor(a7, 8);

    if ((l & 12) == 0) {                 // 4 writer lanes per head
        ushort_t mv[8] = {f2bf(a0), f2bf(a1), f2bf(a2), f2bf(a3),
                          f2bf(a4), f2bf(a5), f2bf(a6), f2bf(a7)};
        const int col = (hh * 4 + hg) * 32 + (l & 3) * 8;
        *(uint4*)&mid[(size_t)nq * 256 + col] = *(uint4*)mv;
    }
}

// =====================================================================
extern "C" void kernel_launch(void* const* d_in, const int* in_sizes, int n_in,
                              void* d_out, int out_size, void* d_ws, size_t ws_size,
                              hipStream_t stream)
{
    const float* q      = (const float*)d_in[0];
    const float* p      = (const float*)d_in[1];
    const float* v      = (const float*)d_in[2];
    const float* W_off  = (const float*)d_in[3];
    const float* b_off  = (const float*)d_in[4];
    const float* W_attn = (const float*)d_in[5];
    const float* b_attn = (const float*)d_in[6];
    const float* W_in   = (const float*)d_in[7];
    const float* b_in   = (const float*)d_in[8];
    const float* W_out  = (const float*)d_in[9];
    const float* b_out  = (const float*)d_in[10];
    float* out = (float*)d_out;

    const int M = M_TOT;                            // 24480

    // workspace layout.  vproj is followed by a 128B ZEROED pad
    // (sampler overread safety).  vbf/qbf are GONE (conversion fused
    // into gemm_proj); mid takes the old vbf slot.
    ushort_t* vproj  = (ushort_t*)d_ws;                          // M*256 bf16 (head-major)
    ushort_t* vpad   = vproj + (size_t)M * 256;                  // 64 ushort = 128B zero pad
    ushort_t* offh   = vpad + 64;                                // M*384 fp16
    ushort_t* mid    = offh + (size_t)M * 384;                   // M*256 bf16
    ushort_t* Tin    = mid + (size_t)M * 256;
    ushort_t* Tcomb  = Tin + 256 * 256;
    ushort_t* Tout   = Tcomb + 384 * 256;
    float*    bcomb  = (float*)(Tout + 256 * 256);

    // 0) weight transposes/fusion + pad zero (small)
    prep_weights_kernel<<<dim3(384), 256, 0, stream>>>(
        W_in, W_off, W_attn, W_out, b_off, b_attn,
        Tin, Tcomb, Tout, bcomb, (int*)vpad);

    // 1) fused convert+projection GEMMs: reads RAW fp32 v/q
    gemm_proj_kernel<<<dim3(192, 3), 256, 0, stream>>>(
        v, q, Tin, Tcomb, b_in, bcomb, vproj, offh);
    // 2) softmax + bilinear sampling -> bf16 mid (head-split, XCD-local)
    msda_sample_kernel<<<dim3(12240), 256, 0, stream>>>(vproj, offh, p, mid);
    // 3) out = mid @ W_out + b_out
    gemm_out_kernel<<<dim3(192, 2), 256, 0, stream>>>(mid, Tout, b_out, out);
}